// Round 1
// baseline (20055.290 us; speedup 1.0000x reference)
//
#include <hip/hip_runtime.h>
#include <hip/hip_bf16.h>

#define NNODES 500000
#define HID 8

// ---------------- degree ----------------
__global__ void deg_kernel(const int* __restrict__ dst, int E, float* __restrict__ degf) {
    int stride = gridDim.x * blockDim.x;
    for (int e = blockIdx.x * blockDim.x + threadIdx.x; e < E; e += stride) {
        atomicAdd(&degf[dst[e]], 1.0f);
    }
}

__global__ void dinv_kernel(const float* __restrict__ degf, float* __restrict__ dinv, int N) {
    int i = blockIdx.x * blockDim.x + threadIdx.x;
    if (i < N) {
        // self-loop adds 1 -> deg >= 1 always, matches rsqrt(max(deg,1))
        dinv[i] = 1.0f / sqrtf(degf[i] + 1.0f);
    }
}

// ---------------- per-node transform: g = dinv * (h @ W); acc init = g (self-loop) ----
template <int IN_DIM>
__global__ void transform_kernel(const float* __restrict__ h, const float* __restrict__ W,
                                 const float* __restrict__ dinv, float* __restrict__ g,
                                 float* __restrict__ acc, int N) {
    int i = blockIdx.x * blockDim.x + threadIdx.x;
    if (i >= N) return;
    float in[IN_DIM];
#pragma unroll
    for (int d = 0; d < IN_DIM; ++d) in[d] = h[(size_t)i * IN_DIM + d];
    float dv = dinv[i];
    float o[HID];
#pragma unroll
    for (int k = 0; k < HID; ++k) {
        float s = 0.0f;
#pragma unroll
        for (int d = 0; d < IN_DIM; ++d) s += in[d] * W[d * HID + k];
        o[k] = s * dv;
    }
    float4 lo = make_float4(o[0], o[1], o[2], o[3]);
    float4 hi = make_float4(o[4], o[5], o[6], o[7]);
    float4* g4 = (float4*)(g + (size_t)i * HID);
    float4* a4 = (float4*)(acc + (size_t)i * HID);
    g4[0] = lo; g4[1] = hi;
    a4[0] = lo; a4[1] = hi;
}

// ---------------- edge scatter: acc[dst] += g[src] ----------------
__global__ void scatter_kernel(const int* __restrict__ src, const int* __restrict__ dst, int E,
                               const float* __restrict__ g, float* __restrict__ acc) {
    int stride = gridDim.x * blockDim.x;
    for (int e = blockIdx.x * blockDim.x + threadIdx.x; e < E; e += stride) {
        int s = src[e];
        int d = dst[e];
        const float4* gs = (const float4*)(g + (size_t)s * HID);
        float4 a = gs[0];
        float4 b = gs[1];
        float* ap = acc + (size_t)d * HID;
        atomicAdd(ap + 0, a.x); atomicAdd(ap + 1, a.y);
        atomicAdd(ap + 2, a.z); atomicAdd(ap + 3, a.w);
        atomicAdd(ap + 4, b.x); atomicAdd(ap + 5, b.y);
        atomicAdd(ap + 6, b.z); atomicAdd(ap + 7, b.w);
    }
}

// ---------------- finalize: h = elu(dinv*acc + b); optional mean-pool accumulate ----
__global__ void finalize_kernel(const float* __restrict__ acc, const float* __restrict__ dinv,
                                const float* __restrict__ bias, float* __restrict__ h, int N,
                                int do_pool, double* __restrict__ pooled) {
    int i = blockIdx.x * blockDim.x + threadIdx.x;
    float v[HID];
    if (i < N) {
        float dv = dinv[i];
        const float4* a4 = (const float4*)(acc + (size_t)i * HID);
        float4 lo = a4[0], hi = a4[1];
        float av[HID] = {lo.x, lo.y, lo.z, lo.w, hi.x, hi.y, hi.z, hi.w};
#pragma unroll
        for (int k = 0; k < HID; ++k) {
            float t = av[k] * dv + bias[k];
            v[k] = t > 0.0f ? t : expm1f(t);
        }
        float4* h4 = (float4*)(h + (size_t)i * HID);
        h4[0] = make_float4(v[0], v[1], v[2], v[3]);
        h4[1] = make_float4(v[4], v[5], v[6], v[7]);
    } else {
#pragma unroll
        for (int k = 0; k < HID; ++k) v[k] = 0.0f;
    }
    if (do_pool) {
        // wave(64) reduce each channel, then cross-wave via LDS, one f64 atomic per block/ch
#pragma unroll
        for (int k = 0; k < HID; ++k) {
            float s = v[k];
            for (int off = 32; off > 0; off >>= 1) s += __shfl_down(s, off);
            v[k] = s;
        }
        __shared__ float sm[4][HID];
        int lane = threadIdx.x & 63;
        int wv = threadIdx.x >> 6;
        if (lane == 0) {
#pragma unroll
            for (int k = 0; k < HID; ++k) sm[wv][k] = v[k];
        }
        __syncthreads();
        if (threadIdx.x == 0) {
#pragma unroll
            for (int k = 0; k < HID; ++k) {
                float s = sm[0][k] + sm[1][k] + sm[2][k] + sm[3][k];
                atomicAdd(&pooled[k], (double)s);
            }
        }
    }
}

// ---------------- head MLP on pooled mean ----------------
__global__ void head_kernel(const double* __restrict__ pooled, const float* __restrict__ Wr1,
                            const float* __restrict__ br1, const float* __restrict__ Wr2,
                            const float* __restrict__ br2, float* __restrict__ out, int N) {
    if (threadIdx.x != 0 || blockIdx.x != 0) return;
    float p[HID];
#pragma unroll
    for (int k = 0; k < HID; ++k) p[k] = (float)(pooled[k] / (double)N);
    float hdn[HID];
#pragma unroll
    for (int j = 0; j < HID; ++j) {
        float s = br1[j];
#pragma unroll
        for (int k = 0; k < HID; ++k) s += p[k] * Wr1[k * HID + j];
        hdn[j] = s > 0.0f ? s : expm1f(s);
    }
    float v = br2[0];
#pragma unroll
    for (int j = 0; j < HID; ++j) v += hdn[j] * Wr2[j];
    out[0] = v;
}

extern "C" void kernel_launch(void* const* d_in, const int* in_sizes, int n_in,
                              void* d_out, int out_size, void* d_ws, size_t ws_size,
                              hipStream_t stream) {
    const float* x   = (const float*)d_in[0];
    const int*   ei  = (const int*)d_in[1];
    const float* W1  = (const float*)d_in[2];
    const float* b1  = (const float*)d_in[3];
    const float* W2  = (const float*)d_in[4];
    const float* b2  = (const float*)d_in[5];
    const float* W3  = (const float*)d_in[6];
    const float* b3  = (const float*)d_in[7];
    const float* Wr1 = (const float*)d_in[8];
    const float* br1 = (const float*)d_in[9];
    const float* Wr2 = (const float*)d_in[10];
    const float* br2 = (const float*)d_in[11];
    float* out = (float*)d_out;

    const int N = NNODES;
    const int E = in_sizes[1] / 2;
    const int* srcp = ei;      // edge_index[0]
    const int* dstp = ei + E;  // edge_index[1]

    // workspace layout (floats unless noted)
    float* degf = (float*)d_ws;            // N
    float* dinv = degf + N;                // N
    float* g    = dinv + N;                // N*HID
    float* acc  = g + (size_t)N * HID;     // N*HID
    float* h    = acc + (size_t)N * HID;   // N*HID
    double* pooled = (double*)(h + (size_t)N * HID);  // HID doubles (8B aligned)

    hipMemsetAsync(degf, 0, (size_t)N * sizeof(float), stream);
    hipMemsetAsync(pooled, 0, HID * sizeof(double), stream);

    const int BLK = 256;
    const int nodeGrid = (N + BLK - 1) / BLK;
    const int edgeGrid = 2048;

    deg_kernel<<<edgeGrid, BLK, 0, stream>>>(dstp, E, degf);
    dinv_kernel<<<nodeGrid, BLK, 0, stream>>>(degf, dinv, N);

    // layer 1 (input x: N x 2)
    transform_kernel<2><<<nodeGrid, BLK, 0, stream>>>(x, W1, dinv, g, acc, N);
    scatter_kernel<<<edgeGrid, BLK, 0, stream>>>(srcp, dstp, E, g, acc);
    finalize_kernel<<<nodeGrid, BLK, 0, stream>>>(acc, dinv, b1, h, N, 0, pooled);

    // layer 2
    transform_kernel<8><<<nodeGrid, BLK, 0, stream>>>(h, W2, dinv, g, acc, N);
    scatter_kernel<<<edgeGrid, BLK, 0, stream>>>(srcp, dstp, E, g, acc);
    finalize_kernel<<<nodeGrid, BLK, 0, stream>>>(acc, dinv, b2, h, N, 0, pooled);

    // layer 3 (+ mean pool)
    transform_kernel<8><<<nodeGrid, BLK, 0, stream>>>(h, W3, dinv, g, acc, N);
    scatter_kernel<<<edgeGrid, BLK, 0, stream>>>(srcp, dstp, E, g, acc);
    finalize_kernel<<<nodeGrid, BLK, 0, stream>>>(acc, dinv, b3, h, N, 1, pooled);

    head_kernel<<<1, 64, 0, stream>>>(pooled, Wr1, br1, Wr2, br2, out, N);
}

// Round 2
// 3756.451 us; speedup vs baseline: 5.3389x; 5.3389x over previous
//
#include <hip/hip_runtime.h>
#include <hip/hip_bf16.h>

#define NNODES 500000
#define HID 8
#define SCAN_BLK 1024

// ---------------- in-degree histogram (int atomics) ----------------
__global__ void hist_kernel(const int* __restrict__ dst, int E, int* __restrict__ deg) {
    int stride = gridDim.x * blockDim.x;
    for (int e = blockIdx.x * blockDim.x + threadIdx.x; e < E; e += stride) {
        atomicAdd(&deg[dst[e]], 1);
    }
}

// ---------------- scan step 1: per-block exclusive scan + block sums ----------------
__global__ void scan1_kernel(const int* __restrict__ deg, int* __restrict__ excl,
                             int* __restrict__ bsum, int N) {
    __shared__ int sm[SCAN_BLK];
    int tid = threadIdx.x;
    int gid = blockIdx.x * SCAN_BLK + tid;
    int v = (gid < N) ? deg[gid] : 0;
    int x = v;
    sm[tid] = x;
    __syncthreads();
    for (int off = 1; off < SCAN_BLK; off <<= 1) {
        int t = (tid >= off) ? sm[tid - off] : 0;
        __syncthreads();
        x += t;
        sm[tid] = x;
        __syncthreads();
    }
    if (gid < N) excl[gid] = x - v;  // exclusive within block
    if (tid == SCAN_BLK - 1) bsum[blockIdx.x] = x;
}

// ---------------- scan step 2: exclusive scan of block sums (single block) ----------------
__global__ void scan2_kernel(int* __restrict__ bsum, int nb) {
    __shared__ int sm[SCAN_BLK];
    int tid = threadIdx.x;
    int v = (tid < nb) ? bsum[tid] : 0;
    int x = v;
    sm[tid] = x;
    __syncthreads();
    for (int off = 1; off < SCAN_BLK; off <<= 1) {
        int t = (tid >= off) ? sm[tid - off] : 0;
        __syncthreads();
        x += t;
        sm[tid] = x;
        __syncthreads();
    }
    if (tid < nb) bsum[tid] = x - v;  // exclusive
}

// ---------------- scan step 3: add block offsets; emit ptr, cursor, dinv ----------------
__global__ void scan3_kernel(int* __restrict__ ptr, const int* __restrict__ bsum,
                             const int* __restrict__ deg, int* __restrict__ cursor,
                             float* __restrict__ dinv, int N, int E) {
    int i = blockIdx.x * blockDim.x + threadIdx.x;
    if (i < N) {
        int p = ptr[i] + bsum[i / SCAN_BLK];
        ptr[i] = p;
        cursor[i] = p;
        dinv[i] = rsqrtf((float)deg[i] + 1.0f);  // self-loop => deg+1 >= 1
    }
    if (i == 0) ptr[N] = E;
}

// ---------------- counting-sort scatter: group src by dst ----------------
__global__ void build_kernel(const int* __restrict__ src, const int* __restrict__ dst, int E,
                             int* __restrict__ cursor, int* __restrict__ ssrc) {
    int stride = gridDim.x * blockDim.x;
    for (int e = blockIdx.x * blockDim.x + threadIdx.x; e < E; e += stride) {
        int d = dst[e];
        int pos = atomicAdd(&cursor[d], 1);
        ssrc[pos] = src[e];
    }
}

// ---------------- per-node transform: g = dinv * (h @ W) ----------------
template <int IN_DIM>
__global__ void transform_kernel(const float* __restrict__ h, const float* __restrict__ W,
                                 const float* __restrict__ dinv, float* __restrict__ g, int N) {
    int i = blockIdx.x * blockDim.x + threadIdx.x;
    if (i >= N) return;
    float in[IN_DIM];
#pragma unroll
    for (int d = 0; d < IN_DIM; ++d) in[d] = h[(size_t)i * IN_DIM + d];
    float dv = dinv[i];
    float o[HID];
#pragma unroll
    for (int k = 0; k < HID; ++k) {
        float s = 0.0f;
#pragma unroll
        for (int d = 0; d < IN_DIM; ++d) s += in[d] * W[d * HID + k];
        o[k] = s * dv;
    }
    float4* g4 = (float4*)(g + (size_t)i * HID);
    g4[0] = make_float4(o[0], o[1], o[2], o[3]);
    g4[1] = make_float4(o[4], o[5], o[6], o[7]);
}

// -------- gather-aggregate + epilogue: h = elu(dinv*(g[i] + sum g[src]) + b) --------
__global__ void agg_kernel(const float* __restrict__ g, const int* __restrict__ ptr,
                           const int* __restrict__ ssrc, const float* __restrict__ dinv,
                           const float* __restrict__ bias, float* __restrict__ h, int N,
                           int do_pool, double* __restrict__ pooled) {
    int i = blockIdx.x * blockDim.x + threadIdx.x;
    float v[HID];
    if (i < N) {
        const float4* gi = (const float4*)(g + (size_t)i * HID);
        float4 a = gi[0], b = gi[1];  // self-loop init
        int s0 = ptr[i], s1 = ptr[i + 1];
        for (int k = s0; k < s1; ++k) {
            int s = ssrc[k];
            const float4* gs = (const float4*)(g + (size_t)s * HID);
            float4 p = gs[0], q = gs[1];
            a.x += p.x; a.y += p.y; a.z += p.z; a.w += p.w;
            b.x += q.x; b.y += q.y; b.z += q.z; b.w += q.w;
        }
        float dv = dinv[i];
        float av[HID] = {a.x, a.y, a.z, a.w, b.x, b.y, b.z, b.w};
#pragma unroll
        for (int k = 0; k < HID; ++k) {
            float t = av[k] * dv + bias[k];
            v[k] = t > 0.0f ? t : expm1f(t);
        }
        float4* h4 = (float4*)(h + (size_t)i * HID);
        h4[0] = make_float4(v[0], v[1], v[2], v[3]);
        h4[1] = make_float4(v[4], v[5], v[6], v[7]);
    } else {
#pragma unroll
        for (int k = 0; k < HID; ++k) v[k] = 0.0f;
    }
    if (do_pool) {
#pragma unroll
        for (int k = 0; k < HID; ++k) {
            float s = v[k];
            for (int off = 32; off > 0; off >>= 1) s += __shfl_down(s, off);
            v[k] = s;
        }
        __shared__ float sm[4][HID];
        int lane = threadIdx.x & 63;
        int wv = threadIdx.x >> 6;
        if (lane == 0) {
#pragma unroll
            for (int k = 0; k < HID; ++k) sm[wv][k] = v[k];
        }
        __syncthreads();
        if (threadIdx.x == 0) {
#pragma unroll
            for (int k = 0; k < HID; ++k) {
                float s = sm[0][k] + sm[1][k] + sm[2][k] + sm[3][k];
                atomicAdd(&pooled[k], (double)s);
            }
        }
    }
}

// ---------------- head MLP on pooled mean ----------------
__global__ void head_kernel(const double* __restrict__ pooled, const float* __restrict__ Wr1,
                            const float* __restrict__ br1, const float* __restrict__ Wr2,
                            const float* __restrict__ br2, float* __restrict__ out, int N) {
    if (threadIdx.x != 0 || blockIdx.x != 0) return;
    float p[HID];
#pragma unroll
    for (int k = 0; k < HID; ++k) p[k] = (float)(pooled[k] / (double)N);
    float hdn[HID];
#pragma unroll
    for (int j = 0; j < HID; ++j) {
        float s = br1[j];
#pragma unroll
        for (int k = 0; k < HID; ++k) s += p[k] * Wr1[k * HID + j];
        hdn[j] = s > 0.0f ? s : expm1f(s);
    }
    float v = br2[0];
#pragma unroll
    for (int j = 0; j < HID; ++j) v += hdn[j] * Wr2[j];
    out[0] = v;
}

extern "C" void kernel_launch(void* const* d_in, const int* in_sizes, int n_in,
                              void* d_out, int out_size, void* d_ws, size_t ws_size,
                              hipStream_t stream) {
    const float* x   = (const float*)d_in[0];
    const int*   ei  = (const int*)d_in[1];
    const float* W1  = (const float*)d_in[2];
    const float* b1  = (const float*)d_in[3];
    const float* W2  = (const float*)d_in[4];
    const float* b2  = (const float*)d_in[5];
    const float* W3  = (const float*)d_in[6];
    const float* b3  = (const float*)d_in[7];
    const float* Wr1 = (const float*)d_in[8];
    const float* br1 = (const float*)d_in[9];
    const float* Wr2 = (const float*)d_in[10];
    const float* br2 = (const float*)d_in[11];
    float* out = (float*)d_out;

    const int N = NNODES;
    const int E = in_sizes[1] / 2;
    const int* srcp = ei;      // edge_index[0]
    const int* dstp = ei + E;  // edge_index[1]

    // workspace layout (pooled first for 8B alignment)
    double* pooled = (double*)d_ws;                  // 8 doubles
    int* deg    = (int*)(pooled + HID);              // N
    int* ptr    = deg + N;                           // N+1
    int* cursor = ptr + N + 1;                       // N
    int* bsum   = cursor + N;                        // up to 1024
    float* dinv = (float*)(bsum + 1024);             // N
    float* g    = dinv + N;                          // N*HID
    float* h    = g + (size_t)N * HID;               // N*HID
    int* ssrc   = (int*)(h + (size_t)N * HID);       // E

    hipMemsetAsync(deg, 0, (size_t)N * sizeof(int), stream);
    hipMemsetAsync(pooled, 0, HID * sizeof(double), stream);

    const int BLK = 256;
    const int nodeGrid = (N + BLK - 1) / BLK;
    const int edgeGrid = 2048;
    const int scanBlocks = (N + SCAN_BLK - 1) / SCAN_BLK;  // 489 <= 1024

    // CSR build (once; reused by all 3 layers)
    hist_kernel<<<edgeGrid, BLK, 0, stream>>>(dstp, E, deg);
    scan1_kernel<<<scanBlocks, SCAN_BLK, 0, stream>>>(deg, ptr, bsum, N);
    scan2_kernel<<<1, SCAN_BLK, 0, stream>>>(bsum, scanBlocks);
    scan3_kernel<<<nodeGrid, BLK, 0, stream>>>(ptr, bsum, deg, cursor, dinv, N, E);
    build_kernel<<<edgeGrid, BLK, 0, stream>>>(srcp, dstp, E, cursor, ssrc);

    // layer 1 (input x: N x 2)
    transform_kernel<2><<<nodeGrid, BLK, 0, stream>>>(x, W1, dinv, g, N);
    agg_kernel<<<nodeGrid, BLK, 0, stream>>>(g, ptr, ssrc, dinv, b1, h, N, 0, pooled);

    // layer 2
    transform_kernel<8><<<nodeGrid, BLK, 0, stream>>>(h, W2, dinv, g, N);
    agg_kernel<<<nodeGrid, BLK, 0, stream>>>(g, ptr, ssrc, dinv, b2, h, N, 0, pooled);

    // layer 3 (+ mean pool)
    transform_kernel<8><<<nodeGrid, BLK, 0, stream>>>(h, W3, dinv, g, N);
    agg_kernel<<<nodeGrid, BLK, 0, stream>>>(g, ptr, ssrc, dinv, b3, h, N, 1, pooled);

    head_kernel<<<1, 64, 0, stream>>>(pooled, Wr1, br1, Wr2, br2, out, N);
}

// Round 3
// 2061.714 us; speedup vs baseline: 9.7275x; 1.8220x over previous
//
#include <hip/hip_runtime.h>
#include <hip/hip_bf16.h>

#define NNODES 500000
#define HID 8
#define BIN_SHIFT 8
#define BIN_NODES 256          // nodes per bin
#define NBIN 1954              // ceil(500000/256)
#define SCAN_BLK 1024
#define CHUNK 32768            // edges per binscatter block
#define BUFCAP 12288           // per-bin edge cap: mean 8192, +45 sigma -> never hit

// ---------------- coarse bin histogram ----------------
__global__ void binhist_kernel(const int* __restrict__ dst, int E, int* __restrict__ gbinhist) {
    __shared__ int hist[NBIN];
    for (int b = threadIdx.x; b < NBIN; b += blockDim.x) hist[b] = 0;
    __syncthreads();
    int stride = gridDim.x * blockDim.x;
    for (int e = blockIdx.x * blockDim.x + threadIdx.x; e < E; e += stride)
        atomicAdd(&hist[dst[e] >> BIN_SHIFT], 1);
    __syncthreads();
    for (int b = threadIdx.x; b < NBIN; b += blockDim.x) {
        int c = hist[b];
        if (c) atomicAdd(&gbinhist[b], c);
    }
}

// ---------------- scan step 1: per-block exclusive scan + block sums ----------------
__global__ void scan1_kernel(const int* __restrict__ deg, int* __restrict__ excl,
                             int* __restrict__ bsum, int N) {
    __shared__ int sm[SCAN_BLK];
    int tid = threadIdx.x;
    int gid = blockIdx.x * SCAN_BLK + tid;
    int v = (gid < N) ? deg[gid] : 0;
    int x = v;
    sm[tid] = x;
    __syncthreads();
    for (int off = 1; off < SCAN_BLK; off <<= 1) {
        int t = (tid >= off) ? sm[tid - off] : 0;
        __syncthreads();
        x += t;
        sm[tid] = x;
        __syncthreads();
    }
    if (gid < N) excl[gid] = x - v;
    if (tid == SCAN_BLK - 1) bsum[blockIdx.x] = x;
}

// ---------------- scan step 2: exclusive scan of block sums ----------------
__global__ void scan2_kernel(int* __restrict__ bsum, int nb) {
    __shared__ int sm[SCAN_BLK];
    int tid = threadIdx.x;
    int v = (tid < nb) ? bsum[tid] : 0;
    int x = v;
    sm[tid] = x;
    __syncthreads();
    for (int off = 1; off < SCAN_BLK; off <<= 1) {
        int t = (tid >= off) ? sm[tid - off] : 0;
        __syncthreads();
        x += t;
        sm[tid] = x;
        __syncthreads();
    }
    if (tid < nb) bsum[tid] = x - v;
}

// ---------------- combine: ptr_bins + init gcursor ----------------
__global__ void scan3b_kernel(const int* __restrict__ binexcl, const int* __restrict__ bsum,
                              int* __restrict__ ptr_bins, int* __restrict__ gcursor, int E) {
    int i = blockIdx.x * blockDim.x + threadIdx.x;
    if (i < NBIN) {
        int p = binexcl[i] + bsum[i / SCAN_BLK];
        ptr_bins[i] = p;
        gcursor[i] = p;
    }
    if (i == 0) ptr_bins[NBIN] = E;
}

// -------- phase A: scatter packed (src<<8 | dst_local) into coarse-bin regions --------
__global__ void binscatter_kernel(const int* __restrict__ src, const int* __restrict__ dst,
                                  int E, int* __restrict__ gcursor, int* __restrict__ packed) {
    __shared__ int hist[NBIN];
    __shared__ int base[NBIN];
    int tid = threadIdx.x;
    int e0 = blockIdx.x * CHUNK;
    int e1 = min(E, e0 + CHUNK);
    for (int b = tid; b < NBIN; b += blockDim.x) hist[b] = 0;
    __syncthreads();
    for (int e = e0 + tid; e < e1; e += blockDim.x)
        atomicAdd(&hist[dst[e] >> BIN_SHIFT], 1);
    __syncthreads();
    for (int b = tid; b < NBIN; b += blockDim.x) {
        int c = hist[b];
        base[b] = c ? atomicAdd(&gcursor[b], c) : 0;
    }
    __syncthreads();
    for (int e = e0 + tid; e < e1; e += blockDim.x) {
        int d = dst[e];
        int b = d >> BIN_SHIFT;
        int pos = atomicAdd(&base[b], 1);
        packed[pos] = (src[e] << BIN_SHIFT) | (d & (BIN_NODES - 1));
    }
}

// -------- phase B: per-bin LDS sort -> final ssrc (in place), ptr, dinv --------
__global__ void binsort_kernel(const int* __restrict__ ptr_bins, int* __restrict__ ssrc,
                               int* __restrict__ ptr, float* __restrict__ dinv, int N, int E) {
    __shared__ int buf[BUFCAP];
    __shared__ int hist[BIN_NODES];
    __shared__ int scn[BIN_NODES];
    __shared__ int cursor[BIN_NODES];
    int bin = blockIdx.x;
    int tid = threadIdx.x;
    int base = ptr_bins[bin];
    int len = min(ptr_bins[bin + 1] - base, BUFCAP);  // cap never hit for this input
    int node_base = bin << BIN_SHIFT;
    int nn = min(BIN_NODES, N - node_base);
    if (tid < BIN_NODES) hist[tid] = 0;
    __syncthreads();
    // stage region in LDS + histogram local dst
    for (int k = tid; k < len; k += blockDim.x) {
        int v = ssrc[base + k];
        buf[k] = v;
        atomicAdd(&hist[v & (BIN_NODES - 1)], 1);
    }
    __syncthreads();
    // inclusive scan of hist over 256 (Hillis-Steele)
    int orig = (tid < BIN_NODES) ? hist[tid] : 0;
    int x = orig;
    if (tid < BIN_NODES) scn[tid] = x;
    __syncthreads();
    for (int off = 1; off < BIN_NODES; off <<= 1) {
        int t = (tid >= off && tid < BIN_NODES) ? scn[tid - off] : 0;
        __syncthreads();
        if (tid < BIN_NODES) { x += t; scn[tid] = x; }
        __syncthreads();
    }
    if (tid < nn) {
        int ex = x - orig;  // exclusive
        ptr[node_base + tid] = base + ex;
        cursor[tid] = ex;
        dinv[node_base + tid] = rsqrtf((float)orig + 1.0f);  // self-loop => deg+1
    }
    if (bin == NBIN - 1 && tid == 0) ptr[N] = E;
    __syncthreads();
    // scatter from LDS into final (sorted-by-dst) positions, in place
    for (int k = tid; k < len; k += blockDim.x) {
        int v = buf[k];
        int pos = atomicAdd(&cursor[v & (BIN_NODES - 1)], 1);
        ssrc[base + pos] = v >> BIN_SHIFT;
    }
}

// ---------------- per-node transform: g = dinv * (h @ W) ----------------
template <int IN_DIM>
__global__ void transform_kernel(const float* __restrict__ h, const float* __restrict__ W,
                                 const float* __restrict__ dinv, float* __restrict__ g, int N) {
    int i = blockIdx.x * blockDim.x + threadIdx.x;
    if (i >= N) return;
    float in[IN_DIM];
#pragma unroll
    for (int d = 0; d < IN_DIM; ++d) in[d] = h[(size_t)i * IN_DIM + d];
    float dv = dinv[i];
    float o[HID];
#pragma unroll
    for (int k = 0; k < HID; ++k) {
        float s = 0.0f;
#pragma unroll
        for (int d = 0; d < IN_DIM; ++d) s += in[d] * W[d * HID + k];
        o[k] = s * dv;
    }
    float4* g4 = (float4*)(g + (size_t)i * HID);
    g4[0] = make_float4(o[0], o[1], o[2], o[3]);
    g4[1] = make_float4(o[4], o[5], o[6], o[7]);
}

// -------- gather-aggregate + epilogue: h = elu(dinv*(g[i] + sum g[src]) + b) --------
__global__ void agg_kernel(const float* __restrict__ g, const int* __restrict__ ptr,
                           const int* __restrict__ ssrc, const float* __restrict__ dinv,
                           const float* __restrict__ bias, float* __restrict__ h, int N,
                           int do_pool, double* __restrict__ pooled) {
    int i = blockIdx.x * blockDim.x + threadIdx.x;
    float v[HID];
    if (i < N) {
        const float4* gi = (const float4*)(g + (size_t)i * HID);
        float4 a = gi[0], b = gi[1];  // self-loop init
        int s0 = ptr[i], s1 = ptr[i + 1];
        for (int k = s0; k < s1; ++k) {
            int s = ssrc[k];
            const float4* gs = (const float4*)(g + (size_t)s * HID);
            float4 p = gs[0], q = gs[1];
            a.x += p.x; a.y += p.y; a.z += p.z; a.w += p.w;
            b.x += q.x; b.y += q.y; b.z += q.z; b.w += q.w;
        }
        float dv = dinv[i];
        float av[HID] = {a.x, a.y, a.z, a.w, b.x, b.y, b.z, b.w};
#pragma unroll
        for (int k = 0; k < HID; ++k) {
            float t = av[k] * dv + bias[k];
            v[k] = t > 0.0f ? t : expm1f(t);
        }
        float4* h4 = (float4*)(h + (size_t)i * HID);
        h4[0] = make_float4(v[0], v[1], v[2], v[3]);
        h4[1] = make_float4(v[4], v[5], v[6], v[7]);
    } else {
#pragma unroll
        for (int k = 0; k < HID; ++k) v[k] = 0.0f;
    }
    if (do_pool) {
#pragma unroll
        for (int k = 0; k < HID; ++k) {
            float s = v[k];
            for (int off = 32; off > 0; off >>= 1) s += __shfl_down(s, off);
            v[k] = s;
        }
        __shared__ float sm[4][HID];
        int lane = threadIdx.x & 63;
        int wv = threadIdx.x >> 6;
        if (lane == 0) {
#pragma unroll
            for (int k = 0; k < HID; ++k) sm[wv][k] = v[k];
        }
        __syncthreads();
        if (threadIdx.x == 0) {
#pragma unroll
            for (int k = 0; k < HID; ++k) {
                float s = sm[0][k] + sm[1][k] + sm[2][k] + sm[3][k];
                atomicAdd(&pooled[k], (double)s);
            }
        }
    }
}

// ---------------- head MLP on pooled mean ----------------
__global__ void head_kernel(const double* __restrict__ pooled, const float* __restrict__ Wr1,
                            const float* __restrict__ br1, const float* __restrict__ Wr2,
                            const float* __restrict__ br2, float* __restrict__ out, int N) {
    if (threadIdx.x != 0 || blockIdx.x != 0) return;
    float p[HID];
#pragma unroll
    for (int k = 0; k < HID; ++k) p[k] = (float)(pooled[k] / (double)N);
    float hdn[HID];
#pragma unroll
    for (int j = 0; j < HID; ++j) {
        float s = br1[j];
#pragma unroll
        for (int k = 0; k < HID; ++k) s += p[k] * Wr1[k * HID + j];
        hdn[j] = s > 0.0f ? s : expm1f(s);
    }
    float v = br2[0];
#pragma unroll
    for (int j = 0; j < HID; ++j) v += hdn[j] * Wr2[j];
    out[0] = v;
}

extern "C" void kernel_launch(void* const* d_in, const int* in_sizes, int n_in,
                              void* d_out, int out_size, void* d_ws, size_t ws_size,
                              hipStream_t stream) {
    const float* x   = (const float*)d_in[0];
    const int*   ei  = (const int*)d_in[1];
    const float* W1  = (const float*)d_in[2];
    const float* b1  = (const float*)d_in[3];
    const float* W2  = (const float*)d_in[4];
    const float* b2  = (const float*)d_in[5];
    const float* W3  = (const float*)d_in[6];
    const float* b3  = (const float*)d_in[7];
    const float* Wr1 = (const float*)d_in[8];
    const float* br1 = (const float*)d_in[9];
    const float* Wr2 = (const float*)d_in[10];
    const float* br2 = (const float*)d_in[11];
    float* out = (float*)d_out;

    const int N = NNODES;
    const int E = in_sizes[1] / 2;
    const int* srcp = ei;      // edge_index[0]
    const int* dstp = ei + E;  // edge_index[1]

    // workspace layout
    double* pooled  = (double*)d_ws;                    // 8 doubles
    int* gbinhist   = (int*)(pooled + HID);             // NBIN
    int* binexcl    = gbinhist + NBIN;                  // NBIN
    int* bsum       = binexcl + NBIN;                   // 1024
    int* ptr_bins   = bsum + 1024;                      // NBIN+1
    int* gcursor    = ptr_bins + NBIN + 1;              // NBIN
    int* ptr        = gcursor + NBIN;                   // N+1
    float* dinv     = (float*)(ptr + N + 1);            // N
    float* g        = dinv + N;                         // N*HID
    float* h        = g + (size_t)N * HID;              // N*HID
    int* ssrc       = (int*)(h + (size_t)N * HID);      // E (packed staging, then final)

    hipMemsetAsync(gbinhist, 0, NBIN * sizeof(int), stream);
    hipMemsetAsync(pooled, 0, HID * sizeof(double), stream);

    const int BLK = 256;
    const int nodeGrid = (N + BLK - 1) / BLK;

    // CSR build (two-level LDS-staged counting sort; also produces ptr + dinv)
    binhist_kernel<<<512, BLK, 0, stream>>>(dstp, E, gbinhist);
    scan1_kernel<<<(NBIN + SCAN_BLK - 1) / SCAN_BLK, SCAN_BLK, 0, stream>>>(gbinhist, binexcl, bsum, NBIN);
    scan2_kernel<<<1, SCAN_BLK, 0, stream>>>(bsum, (NBIN + SCAN_BLK - 1) / SCAN_BLK);
    scan3b_kernel<<<(NBIN + BLK - 1) / BLK, BLK, 0, stream>>>(binexcl, bsum, ptr_bins, gcursor, E);
    binscatter_kernel<<<(E + CHUNK - 1) / CHUNK, BLK, 0, stream>>>(srcp, dstp, E, gcursor, ssrc);
    binsort_kernel<<<NBIN, BLK, 0, stream>>>(ptr_bins, ssrc, ptr, dinv, N, E);

    // layer 1 (input x: N x 2)
    transform_kernel<2><<<nodeGrid, BLK, 0, stream>>>(x, W1, dinv, g, N);
    agg_kernel<<<nodeGrid, BLK, 0, stream>>>(g, ptr, ssrc, dinv, b1, h, N, 0, pooled);

    // layer 2
    transform_kernel<8><<<nodeGrid, BLK, 0, stream>>>(h, W2, dinv, g, N);
    agg_kernel<<<nodeGrid, BLK, 0, stream>>>(g, ptr, ssrc, dinv, b2, h, N, 0, pooled);

    // layer 3 (+ mean pool)
    transform_kernel<8><<<nodeGrid, BLK, 0, stream>>>(h, W3, dinv, g, N);
    agg_kernel<<<nodeGrid, BLK, 0, stream>>>(g, ptr, ssrc, dinv, b3, h, N, 1, pooled);

    head_kernel<<<1, 64, 0, stream>>>(pooled, Wr1, br1, Wr2, br2, out, N);
}

// Round 4
// 1211.083 us; speedup vs baseline: 16.5598x; 1.7024x over previous
//
#include <hip/hip_runtime.h>
#include <hip/hip_fp16.h>

#define NNODES 500000
#define HID 8
#define BIN_SHIFT 8
#define BIN_NODES 256          // nodes per bin
#define NBIN 1954              // ceil(500000/256)
#define SCAN_BLK 1024
#define CHUNK 32768            // edges per binscatter block
#define BUFCAP 12288           // per-bin edge cap: mean 8192 -> never hit

__device__ __forceinline__ unsigned int packh2(float a, float b) {
    __half2 h = __floats2half2_rn(a, b);
    return *reinterpret_cast<unsigned int*>(&h);
}
__device__ __forceinline__ float2 unpackh2(unsigned int u) {
    __half2 h = *reinterpret_cast<__half2*>(&u);
    return __half22float2(h);
}
__device__ __forceinline__ float elu(float t) { return t > 0.0f ? t : expm1f(t); }

// ================= CSR build (same structure as R3) =================
__global__ void binhist_kernel(const int* __restrict__ dst, int E, int* __restrict__ gbinhist) {
    __shared__ int hist[NBIN];
    for (int b = threadIdx.x; b < NBIN; b += blockDim.x) hist[b] = 0;
    __syncthreads();
    int stride = gridDim.x * blockDim.x;
    for (int e = blockIdx.x * blockDim.x + threadIdx.x; e < E; e += stride)
        atomicAdd(&hist[dst[e] >> BIN_SHIFT], 1);
    __syncthreads();
    for (int b = threadIdx.x; b < NBIN; b += blockDim.x) {
        int c = hist[b];
        if (c) atomicAdd(&gbinhist[b], c);
    }
}

__global__ void scan1_kernel(const int* __restrict__ deg, int* __restrict__ excl,
                             int* __restrict__ bsum, int N) {
    __shared__ int sm[SCAN_BLK];
    int tid = threadIdx.x;
    int gid = blockIdx.x * SCAN_BLK + tid;
    int v = (gid < N) ? deg[gid] : 0;
    int x = v;
    sm[tid] = x;
    __syncthreads();
    for (int off = 1; off < SCAN_BLK; off <<= 1) {
        int t = (tid >= off) ? sm[tid - off] : 0;
        __syncthreads();
        x += t;
        sm[tid] = x;
        __syncthreads();
    }
    if (gid < N) excl[gid] = x - v;
    if (tid == SCAN_BLK - 1) bsum[blockIdx.x] = x;
}

__global__ void scan2_kernel(int* __restrict__ bsum, int nb) {
    __shared__ int sm[SCAN_BLK];
    int tid = threadIdx.x;
    int v = (tid < nb) ? bsum[tid] : 0;
    int x = v;
    sm[tid] = x;
    __syncthreads();
    for (int off = 1; off < SCAN_BLK; off <<= 1) {
        int t = (tid >= off) ? sm[tid - off] : 0;
        __syncthreads();
        x += t;
        sm[tid] = x;
        __syncthreads();
    }
    if (tid < nb) bsum[tid] = x - v;
}

__global__ void scan3b_kernel(const int* __restrict__ binexcl, const int* __restrict__ bsum,
                              int* __restrict__ ptr_bins, int* __restrict__ gcursor, int E) {
    int i = blockIdx.x * blockDim.x + threadIdx.x;
    if (i < NBIN) {
        int p = binexcl[i] + bsum[i / SCAN_BLK];
        ptr_bins[i] = p;
        gcursor[i] = p;
    }
    if (i == 0) ptr_bins[NBIN] = E;
}

__global__ void binscatter_kernel(const int* __restrict__ src, const int* __restrict__ dst,
                                  int E, int* __restrict__ gcursor, int* __restrict__ packed) {
    __shared__ int hist[NBIN];
    __shared__ int base[NBIN];
    int tid = threadIdx.x;
    int e0 = blockIdx.x * CHUNK;
    int e1 = min(E, e0 + CHUNK);
    for (int b = tid; b < NBIN; b += blockDim.x) hist[b] = 0;
    __syncthreads();
    for (int e = e0 + tid; e < e1; e += blockDim.x)
        atomicAdd(&hist[dst[e] >> BIN_SHIFT], 1);
    __syncthreads();
    for (int b = tid; b < NBIN; b += blockDim.x) {
        int c = hist[b];
        base[b] = c ? atomicAdd(&gcursor[b], c) : 0;
    }
    __syncthreads();
    for (int e = e0 + tid; e < e1; e += blockDim.x) {
        int d = dst[e];
        int b = d >> BIN_SHIFT;
        int pos = atomicAdd(&base[b], 1);
        packed[pos] = (src[e] << BIN_SHIFT) | (d & (BIN_NODES - 1));
    }
}

__global__ void binsort_kernel(const int* __restrict__ ptr_bins, int* __restrict__ ssrc,
                               int* __restrict__ ptr, float* __restrict__ dinv, int N, int E) {
    __shared__ int buf[BUFCAP];
    __shared__ int hist[BIN_NODES];
    __shared__ int scn[BIN_NODES];
    __shared__ int cursor[BIN_NODES];
    int bin = blockIdx.x;
    int tid = threadIdx.x;
    int base = ptr_bins[bin];
    int len = min(ptr_bins[bin + 1] - base, BUFCAP);
    int node_base = bin << BIN_SHIFT;
    int nn = min(BIN_NODES, N - node_base);
    if (tid < BIN_NODES) hist[tid] = 0;
    __syncthreads();
    for (int k = tid; k < len; k += blockDim.x) {
        int v = ssrc[base + k];
        buf[k] = v;
        atomicAdd(&hist[v & (BIN_NODES - 1)], 1);
    }
    __syncthreads();
    int orig = (tid < BIN_NODES) ? hist[tid] : 0;
    int x = orig;
    if (tid < BIN_NODES) scn[tid] = x;
    __syncthreads();
    for (int off = 1; off < BIN_NODES; off <<= 1) {
        int t = (tid >= off && tid < BIN_NODES) ? scn[tid - off] : 0;
        __syncthreads();
        if (tid < BIN_NODES) { x += t; scn[tid] = x; }
        __syncthreads();
    }
    if (tid < nn) {
        int ex = x - orig;
        ptr[node_base + tid] = base + ex;
        cursor[tid] = ex;
        dinv[node_base + tid] = rsqrtf((float)orig + 1.0f);
    }
    if (bin == NBIN - 1 && tid == 0) ptr[N] = E;
    __syncthreads();
    for (int k = tid; k < len; k += blockDim.x) {
        int v = buf[k];
        int pos = atomicAdd(&cursor[v & (BIN_NODES - 1)], 1);
        ssrc[base + pos] = v >> BIN_SHIFT;
    }
}

// ================= layer pipeline =================
// prep: t1[i] = fp16x2(dinv_i * x_i)   (2 MB table)
__global__ void prep1_kernel(const float* __restrict__ x, const float* __restrict__ dinv,
                             unsigned int* __restrict__ t1, int N) {
    int i = blockIdx.x * blockDim.x + threadIdx.x;
    if (i >= N) return;
    float2 xv = *reinterpret_cast<const float2*>(x + 2 * (size_t)i);
    float dv = dinv[i];
    t1[i] = packh2(dv * xv.x, dv * xv.y);
}

// layer1: gather 2ch; apply W1 post-agg; elu; emit layer2 tables (fp16 4ch each)
__global__ void agg1_kernel(const unsigned int* __restrict__ t1, const int* __restrict__ ptr,
                            const int* __restrict__ ssrc, const float* __restrict__ dinv,
                            const float* __restrict__ W1, const float* __restrict__ b1,
                            const float* __restrict__ W2,
                            uint2* __restrict__ t2A, uint2* __restrict__ t2B, int N) {
    int i = blockIdx.x * blockDim.x + threadIdx.x;
    if (i >= N) return;
    float2 s = unpackh2(t1[i]);  // self-loop
    int s0 = ptr[i], s1 = ptr[i + 1];
#pragma unroll 4
    for (int k = s0; k < s1; ++k) {
        float2 p = unpackh2(t1[ssrc[k]]);
        s.x += p.x; s.y += p.y;
    }
    float dv = dinv[i];
    float h[HID];
#pragma unroll
    for (int c = 0; c < HID; ++c)
        h[c] = elu(dv * (s.x * W1[c] + s.y * W1[HID + c]) + b1[c]);
    float g[HID];
#pragma unroll
    for (int c = 0; c < HID; ++c) {
        float acc = 0.0f;
#pragma unroll
        for (int k = 0; k < HID; ++k) acc += h[k] * W2[k * HID + c];
        g[c] = dv * acc;
    }
    t2A[i] = make_uint2(packh2(g[0], g[1]), packh2(g[2], g[3]));
    t2B[i] = make_uint2(packh2(g[4], g[5]), packh2(g[6], g[7]));
}

// layer2 pass A: channels 0-3 -> h2 low half (f32)
__global__ void agg2A_kernel(const uint2* __restrict__ tab, const int* __restrict__ ptr,
                             const int* __restrict__ ssrc, const float* __restrict__ dinv,
                             const float* __restrict__ b2, float4* __restrict__ hlo, int N) {
    int i = blockIdx.x * blockDim.x + threadIdx.x;
    if (i >= N) return;
    uint2 u = tab[i];
    float2 a = unpackh2(u.x), b = unpackh2(u.y);
    float s0 = a.x, s1 = a.y, s2 = b.x, s3 = b.y;
    int e0 = ptr[i], e1 = ptr[i + 1];
#pragma unroll 4
    for (int k = e0; k < e1; ++k) {
        uint2 v = tab[ssrc[k]];
        float2 p = unpackh2(v.x), q = unpackh2(v.y);
        s0 += p.x; s1 += p.y; s2 += q.x; s3 += q.y;
    }
    float dv = dinv[i];
    hlo[i] = make_float4(elu(dv * s0 + b2[0]), elu(dv * s1 + b2[1]),
                         elu(dv * s2 + b2[2]), elu(dv * s3 + b2[3]));
}

// layer2 pass B: channels 4-7; combine with hlo; emit layer3 tables
__global__ void agg2B_kernel(const uint2* __restrict__ tab, const int* __restrict__ ptr,
                             const int* __restrict__ ssrc, const float* __restrict__ dinv,
                             const float* __restrict__ b2, const float4* __restrict__ hlo,
                             const float* __restrict__ W3,
                             uint2* __restrict__ t3A, uint2* __restrict__ t3B, int N) {
    int i = blockIdx.x * blockDim.x + threadIdx.x;
    if (i >= N) return;
    uint2 u = tab[i];
    float2 a = unpackh2(u.x), b = unpackh2(u.y);
    float s0 = a.x, s1 = a.y, s2 = b.x, s3 = b.y;
    int e0 = ptr[i], e1 = ptr[i + 1];
#pragma unroll 4
    for (int k = e0; k < e1; ++k) {
        uint2 v = tab[ssrc[k]];
        float2 p = unpackh2(v.x), q = unpackh2(v.y);
        s0 += p.x; s1 += p.y; s2 += q.x; s3 += q.y;
    }
    float dv = dinv[i];
    float4 lo = hlo[i];
    float h[HID] = {lo.x, lo.y, lo.z, lo.w,
                    elu(dv * s0 + b2[4]), elu(dv * s1 + b2[5]),
                    elu(dv * s2 + b2[6]), elu(dv * s3 + b2[7])};
    float g[HID];
#pragma unroll
    for (int c = 0; c < HID; ++c) {
        float acc = 0.0f;
#pragma unroll
        for (int k = 0; k < HID; ++k) acc += h[k] * W3[k * HID + c];
        g[c] = dv * acc;
    }
    t3A[i] = make_uint2(packh2(g[0], g[1]), packh2(g[2], g[3]));
    t3B[i] = make_uint2(packh2(g[4], g[5]), packh2(g[6], g[7]));
}

// layer3 passes: 4 channels each, fused mean-pool (no per-node output)
__global__ void agg3_kernel(const uint2* __restrict__ tab, const int* __restrict__ ptr,
                            const int* __restrict__ ssrc, const float* __restrict__ dinv,
                            const float* __restrict__ b3, int bofs,
                            double* __restrict__ pooled, int N) {
    int i = blockIdx.x * blockDim.x + threadIdx.x;
    float v[4] = {0.f, 0.f, 0.f, 0.f};
    if (i < N) {
        uint2 u = tab[i];
        float2 a = unpackh2(u.x), b = unpackh2(u.y);
        float s0 = a.x, s1 = a.y, s2 = b.x, s3 = b.y;
        int e0 = ptr[i], e1 = ptr[i + 1];
#pragma unroll 4
        for (int k = e0; k < e1; ++k) {
            uint2 w = tab[ssrc[k]];
            float2 p = unpackh2(w.x), q = unpackh2(w.y);
            s0 += p.x; s1 += p.y; s2 += q.x; s3 += q.y;
        }
        float dv = dinv[i];
        v[0] = elu(dv * s0 + b3[bofs + 0]);
        v[1] = elu(dv * s1 + b3[bofs + 1]);
        v[2] = elu(dv * s2 + b3[bofs + 2]);
        v[3] = elu(dv * s3 + b3[bofs + 3]);
    }
#pragma unroll
    for (int c = 0; c < 4; ++c) {
        float s = v[c];
        for (int off = 32; off > 0; off >>= 1) s += __shfl_down(s, off);
        v[c] = s;
    }
    __shared__ float sm[4][4];
    int lane = threadIdx.x & 63;
    int wv = threadIdx.x >> 6;
    if (lane == 0) {
#pragma unroll
        for (int c = 0; c < 4; ++c) sm[wv][c] = v[c];
    }
    __syncthreads();
    if (threadIdx.x == 0) {
#pragma unroll
        for (int c = 0; c < 4; ++c) {
            float s = sm[0][c] + sm[1][c] + sm[2][c] + sm[3][c];
            atomicAdd(&pooled[bofs + c], (double)s);
        }
    }
}

__global__ void head_kernel(const double* __restrict__ pooled, const float* __restrict__ Wr1,
                            const float* __restrict__ br1, const float* __restrict__ Wr2,
                            const float* __restrict__ br2, float* __restrict__ out, int N) {
    if (threadIdx.x != 0 || blockIdx.x != 0) return;
    float p[HID];
#pragma unroll
    for (int k = 0; k < HID; ++k) p[k] = (float)(pooled[k] / (double)N);
    float hdn[HID];
#pragma unroll
    for (int j = 0; j < HID; ++j) {
        float s = br1[j];
#pragma unroll
        for (int k = 0; k < HID; ++k) s += p[k] * Wr1[k * HID + j];
        hdn[j] = elu(s);
    }
    float v = br2[0];
#pragma unroll
    for (int j = 0; j < HID; ++j) v += hdn[j] * Wr2[j];
    out[0] = v;
}

extern "C" void kernel_launch(void* const* d_in, const int* in_sizes, int n_in,
                              void* d_out, int out_size, void* d_ws, size_t ws_size,
                              hipStream_t stream) {
    const float* x   = (const float*)d_in[0];
    const int*   ei  = (const int*)d_in[1];
    const float* W1  = (const float*)d_in[2];
    const float* b1  = (const float*)d_in[3];
    const float* W2  = (const float*)d_in[4];
    const float* b2  = (const float*)d_in[5];
    const float* W3  = (const float*)d_in[6];
    const float* b3  = (const float*)d_in[7];
    const float* Wr1 = (const float*)d_in[8];
    const float* br1 = (const float*)d_in[9];
    const float* Wr2 = (const float*)d_in[10];
    const float* br2 = (const float*)d_in[11];
    float* out = (float*)d_out;

    const int N = NNODES;
    const int E = in_sizes[1] / 2;
    const int* srcp = ei;      // edge_index[0]
    const int* dstp = ei + E;  // edge_index[1]

    // workspace layout
    double* pooled    = (double*)d_ws;                       // 8 doubles
    uint2* t2A        = (uint2*)(pooled + HID);              // N (8B each)
    uint2* t2B        = t2A + N;
    uint2* t3A        = t2B + N;
    uint2* t3B        = t3A + N;
    float4* hlo       = (float4*)(t3B + N);                  // N (16B) — offset 64+16e6, /16 ok
    unsigned int* t1  = (unsigned int*)(hlo + N);            // N
    int* gbinhist     = (int*)(t1 + N);                      // NBIN
    int* binexcl      = gbinhist + NBIN;                     // NBIN
    int* bsum         = binexcl + NBIN;                      // 1024
    int* ptr_bins     = bsum + 1024;                         // NBIN+1
    int* gcursor      = ptr_bins + NBIN + 1;                 // NBIN
    int* ptr          = gcursor + NBIN;                      // N+1
    float* dinv       = (float*)(ptr + N + 1);               // N
    int* ssrc         = (int*)(dinv + N);                    // E

    hipMemsetAsync(gbinhist, 0, NBIN * sizeof(int), stream);
    hipMemsetAsync(pooled, 0, HID * sizeof(double), stream);

    const int BLK = 256;
    const int nodeGrid = (N + BLK - 1) / BLK;

    // CSR build
    binhist_kernel<<<512, BLK, 0, stream>>>(dstp, E, gbinhist);
    scan1_kernel<<<(NBIN + SCAN_BLK - 1) / SCAN_BLK, SCAN_BLK, 0, stream>>>(gbinhist, binexcl, bsum, NBIN);
    scan2_kernel<<<1, SCAN_BLK, 0, stream>>>(bsum, (NBIN + SCAN_BLK - 1) / SCAN_BLK);
    scan3b_kernel<<<(NBIN + BLK - 1) / BLK, BLK, 0, stream>>>(binexcl, bsum, ptr_bins, gcursor, E);
    binscatter_kernel<<<(E + CHUNK - 1) / CHUNK, BLK, 0, stream>>>(srcp, dstp, E, gcursor, ssrc);
    binsort_kernel<<<NBIN, BLK, 0, stream>>>(ptr_bins, ssrc, ptr, dinv, N, E);

    // layers (transforms fused into epilogues; fp16 L2-resident gather tables)
    prep1_kernel<<<nodeGrid, BLK, 0, stream>>>(x, dinv, t1, N);
    agg1_kernel<<<nodeGrid, BLK, 0, stream>>>(t1, ptr, ssrc, dinv, W1, b1, W2, t2A, t2B, N);
    agg2A_kernel<<<nodeGrid, BLK, 0, stream>>>(t2A, ptr, ssrc, dinv, b2, hlo, N);
    agg2B_kernel<<<nodeGrid, BLK, 0, stream>>>(t2B, ptr, ssrc, dinv, b2, hlo, W3, t3A, t3B, N);
    agg3_kernel<<<nodeGrid, BLK, 0, stream>>>(t3A, ptr, ssrc, dinv, b3, 0, pooled, N);
    agg3_kernel<<<nodeGrid, BLK, 0, stream>>>(t3B, ptr, ssrc, dinv, b3, 4, pooled, N);

    head_kernel<<<1, 64, 0, stream>>>(pooled, Wr1, br1, Wr2, br2, out, N);
}

// Round 5
// 981.027 us; speedup vs baseline: 20.4431x; 1.2345x over previous
//
#include <hip/hip_runtime.h>
#include <hip/hip_fp16.h>

#define NNODES 500000
#define HID 8
#define BIN_SHIFT 8
#define BIN_NODES 256          // nodes per bin
#define NBIN 1954              // ceil(500000/256)
#define SCAN_BLK 1024
#define CHUNK 65536            // edges per binscatter block (runs ~134B -> low write amp)
#define BUFCAP 12288           // per-bin LDS staging cap (mean 8192, +45 sigma)

__device__ __forceinline__ unsigned int packh2(float a, float b) {
    __half2 h = __floats2half2_rn(a, b);
    return *reinterpret_cast<unsigned int*>(&h);
}
__device__ __forceinline__ float2 unpackh2(unsigned int u) {
    __half2 h = *reinterpret_cast<__half2*>(&u);
    return __half22float2(h);
}
__device__ __forceinline__ float elu(float t) { return t > 0.0f ? t : expm1f(t); }

// ================= CSR build =================
__global__ void binhist_kernel(const int* __restrict__ dst, int E, int* __restrict__ gbinhist) {
    __shared__ int hist[NBIN];
    for (int b = threadIdx.x; b < NBIN; b += blockDim.x) hist[b] = 0;
    __syncthreads();
    int stride = gridDim.x * blockDim.x;
    const int4* d4 = (const int4*)dst;
    int n4 = E >> 2;
    for (int e = blockIdx.x * blockDim.x + threadIdx.x; e < n4; e += stride) {
        int4 d = d4[e];
        atomicAdd(&hist[d.x >> BIN_SHIFT], 1);
        atomicAdd(&hist[d.y >> BIN_SHIFT], 1);
        atomicAdd(&hist[d.z >> BIN_SHIFT], 1);
        atomicAdd(&hist[d.w >> BIN_SHIFT], 1);
    }
    // tail (E % 4)
    int tail0 = n4 << 2;
    for (int e = tail0 + blockIdx.x * blockDim.x + threadIdx.x; e < E; e += stride)
        atomicAdd(&hist[dst[e] >> BIN_SHIFT], 1);
    __syncthreads();
    for (int b = threadIdx.x; b < NBIN; b += blockDim.x) {
        int c = hist[b];
        if (c) atomicAdd(&gbinhist[b], c);
    }
}

__global__ void scan1_kernel(const int* __restrict__ deg, int* __restrict__ excl,
                             int* __restrict__ bsum, int N) {
    __shared__ int sm[SCAN_BLK];
    int tid = threadIdx.x;
    int gid = blockIdx.x * SCAN_BLK + tid;
    int v = (gid < N) ? deg[gid] : 0;
    int x = v;
    sm[tid] = x;
    __syncthreads();
    for (int off = 1; off < SCAN_BLK; off <<= 1) {
        int t = (tid >= off) ? sm[tid - off] : 0;
        __syncthreads();
        x += t;
        sm[tid] = x;
        __syncthreads();
    }
    if (gid < N) excl[gid] = x - v;
    if (tid == SCAN_BLK - 1) bsum[blockIdx.x] = x;
}

__global__ void scan2_kernel(int* __restrict__ bsum, int nb) {
    __shared__ int sm[SCAN_BLK];
    int tid = threadIdx.x;
    int v = (tid < nb) ? bsum[tid] : 0;
    int x = v;
    sm[tid] = x;
    __syncthreads();
    for (int off = 1; off < SCAN_BLK; off <<= 1) {
        int t = (tid >= off) ? sm[tid - off] : 0;
        __syncthreads();
        x += t;
        sm[tid] = x;
        __syncthreads();
    }
    if (tid < nb) bsum[tid] = x - v;
}

__global__ void scan3b_kernel(const int* __restrict__ binexcl, const int* __restrict__ bsum,
                              int* __restrict__ ptr_bins, int* __restrict__ gcursor, int E) {
    int i = blockIdx.x * blockDim.x + threadIdx.x;
    if (i < NBIN) {
        int p = binexcl[i] + bsum[i / SCAN_BLK];
        ptr_bins[i] = p;
        gcursor[i] = p;
    }
    if (i == 0) ptr_bins[NBIN] = E;
}

// phase A: scatter packed (src<<8 | dst_local) into exact coarse-bin regions
__global__ void binscatter_kernel(const int* __restrict__ src, const int* __restrict__ dst,
                                  int E, int* __restrict__ gcursor, int* __restrict__ packed) {
    __shared__ int hist[NBIN];
    __shared__ int base[NBIN];
    int tid = threadIdx.x;
    int e0 = blockIdx.x * CHUNK;
    int e1 = min(E, e0 + CHUNK);
    int len = e1 - e0;
    for (int b = tid; b < NBIN; b += blockDim.x) hist[b] = 0;
    __syncthreads();
    // histogram (vectorized; chunk start is 64B aligned, len%4==0 for this input)
    int n4 = len >> 2;
    const int4* d4 = (const int4*)(dst + e0);
    for (int k = tid; k < n4; k += blockDim.x) {
        int4 d = d4[k];
        atomicAdd(&hist[d.x >> BIN_SHIFT], 1);
        atomicAdd(&hist[d.y >> BIN_SHIFT], 1);
        atomicAdd(&hist[d.z >> BIN_SHIFT], 1);
        atomicAdd(&hist[d.w >> BIN_SHIFT], 1);
    }
    for (int k = (n4 << 2) + tid; k < len; k += blockDim.x)
        atomicAdd(&hist[dst[e0 + k] >> BIN_SHIFT], 1);
    __syncthreads();
    for (int b = tid; b < NBIN; b += blockDim.x) {
        int c = hist[b];
        base[b] = c ? atomicAdd(&gcursor[b], c) : 0;
    }
    __syncthreads();
    // scatter (dst slice is L2-hot from phase 1)
    const int4* s4 = (const int4*)(src + e0);
    for (int k = tid; k < n4; k += blockDim.x) {
        int4 d = d4[k];
        int4 s = s4[k];
        int p0 = atomicAdd(&base[d.x >> BIN_SHIFT], 1);
        packed[p0] = (s.x << BIN_SHIFT) | (d.x & (BIN_NODES - 1));
        int p1 = atomicAdd(&base[d.y >> BIN_SHIFT], 1);
        packed[p1] = (s.y << BIN_SHIFT) | (d.y & (BIN_NODES - 1));
        int p2 = atomicAdd(&base[d.z >> BIN_SHIFT], 1);
        packed[p2] = (s.z << BIN_SHIFT) | (d.z & (BIN_NODES - 1));
        int p3 = atomicAdd(&base[d.w >> BIN_SHIFT], 1);
        packed[p3] = (s.w << BIN_SHIFT) | (d.w & (BIN_NODES - 1));
    }
    for (int k = (n4 << 2) + tid; k < len; k += blockDim.x) {
        int d = dst[e0 + k];
        int pos = atomicAdd(&base[d >> BIN_SHIFT], 1);
        packed[pos] = (src[e0 + k] << BIN_SHIFT) | (d & (BIN_NODES - 1));
    }
}

// phase B: per-bin LDS sort -> final ssrc (in place), ptr, dinv, t1 (= dinv*x fp16x2)
__global__ void binsort_kernel(const int* __restrict__ ptr_bins, int* __restrict__ ssrc,
                               int* __restrict__ ptr, float* __restrict__ dinv,
                               const float* __restrict__ x, unsigned int* __restrict__ t1,
                               int N, int E) {
    __shared__ int buf[BUFCAP];
    __shared__ int hist[BIN_NODES];
    __shared__ int scn[BIN_NODES];
    __shared__ int cursor[BIN_NODES];
    int bin = blockIdx.x;
    int tid = threadIdx.x;
    int base = ptr_bins[bin];
    int len = min(ptr_bins[bin + 1] - base, BUFCAP);
    int node_base = bin << BIN_SHIFT;
    int nn = min(BIN_NODES, N - node_base);
    if (tid < BIN_NODES) hist[tid] = 0;
    __syncthreads();
    for (int k = tid; k < len; k += blockDim.x) {
        int v = ssrc[base + k];
        buf[k] = v;
        atomicAdd(&hist[v & (BIN_NODES - 1)], 1);
    }
    __syncthreads();
    int orig = (tid < BIN_NODES) ? hist[tid] : 0;
    int x_ = orig;
    if (tid < BIN_NODES) scn[tid] = x_;
    __syncthreads();
    for (int off = 1; off < BIN_NODES; off <<= 1) {
        int t = (tid >= off && tid < BIN_NODES) ? scn[tid - off] : 0;
        __syncthreads();
        if (tid < BIN_NODES) { x_ += t; scn[tid] = x_; }
        __syncthreads();
    }
    if (tid < nn) {
        int ex = x_ - orig;
        int node = node_base + tid;
        ptr[node] = base + ex;
        cursor[tid] = ex;
        float dv = rsqrtf((float)orig + 1.0f);  // self-loop => deg+1
        dinv[node] = dv;
        float2 xv = *reinterpret_cast<const float2*>(x + 2 * (size_t)node);
        t1[node] = packh2(dv * xv.x, dv * xv.y);
    }
    if (bin == NBIN - 1 && tid == 0) ptr[N] = E;
    __syncthreads();
    for (int k = tid; k < len; k += blockDim.x) {
        int v = buf[k];
        int pos = atomicAdd(&cursor[v & (BIN_NODES - 1)], 1);
        ssrc[base + pos] = v >> BIN_SHIFT;
    }
}

// ================= layer pipeline (3 gather passes) =================
// layer1: gather 2ch fp16 (4B rows, 2MB table); epilogue W1->elu->W2 -> t2 (16B rows)
__global__ void agg1_kernel(const unsigned int* __restrict__ t1, const int* __restrict__ ptr,
                            const int* __restrict__ ssrc, const float* __restrict__ dinv,
                            const float* __restrict__ W1, const float* __restrict__ b1,
                            const float* __restrict__ W2, uint4* __restrict__ t2, int N) {
    int i = blockIdx.x * blockDim.x + threadIdx.x;
    if (i >= N) return;
    float2 s = unpackh2(t1[i]);  // self-loop
    int e0 = ptr[i], e1 = ptr[i + 1];
#pragma unroll 4
    for (int k = e0; k < e1; ++k) {
        float2 p = unpackh2(t1[ssrc[k]]);
        s.x += p.x; s.y += p.y;
    }
    float dv = dinv[i];
    float h[HID];
#pragma unroll
    for (int c = 0; c < HID; ++c)
        h[c] = elu(dv * (s.x * W1[c] + s.y * W1[HID + c]) + b1[c]);
    float g[HID];
#pragma unroll
    for (int c = 0; c < HID; ++c) {
        float acc = 0.0f;
#pragma unroll
        for (int k = 0; k < HID; ++k) acc += h[k] * W2[k * HID + c];
        g[c] = dv * acc;
    }
    t2[i] = make_uint4(packh2(g[0], g[1]), packh2(g[2], g[3]),
                       packh2(g[4], g[5]), packh2(g[6], g[7]));
}

// layer2: gather 8ch fp16 (16B rows); epilogue b2->elu->W3 -> t3
__global__ void agg2_kernel(const uint4* __restrict__ tab, const int* __restrict__ ptr,
                            const int* __restrict__ ssrc, const float* __restrict__ dinv,
                            const float* __restrict__ b2, const float* __restrict__ W3,
                            uint4* __restrict__ t3, int N) {
    int i = blockIdx.x * blockDim.x + threadIdx.x;
    if (i >= N) return;
    uint4 u = tab[i];
    float2 p0 = unpackh2(u.x), p1 = unpackh2(u.y), p2 = unpackh2(u.z), p3 = unpackh2(u.w);
    float s0 = p0.x, s1 = p0.y, s2 = p1.x, s3 = p1.y;
    float s4 = p2.x, s5 = p2.y, s6 = p3.x, s7 = p3.y;
    int e0 = ptr[i], e1 = ptr[i + 1];
#pragma unroll 4
    for (int k = e0; k < e1; ++k) {
        uint4 w = tab[ssrc[k]];
        float2 q0 = unpackh2(w.x), q1 = unpackh2(w.y), q2 = unpackh2(w.z), q3 = unpackh2(w.w);
        s0 += q0.x; s1 += q0.y; s2 += q1.x; s3 += q1.y;
        s4 += q2.x; s5 += q2.y; s6 += q3.x; s7 += q3.y;
    }
    float dv = dinv[i];
    float h[HID] = {elu(dv * s0 + b2[0]), elu(dv * s1 + b2[1]),
                    elu(dv * s2 + b2[2]), elu(dv * s3 + b2[3]),
                    elu(dv * s4 + b2[4]), elu(dv * s5 + b2[5]),
                    elu(dv * s6 + b2[6]), elu(dv * s7 + b2[7])};
    float g[HID];
#pragma unroll
    for (int c = 0; c < HID; ++c) {
        float acc = 0.0f;
#pragma unroll
        for (int k = 0; k < HID; ++k) acc += h[k] * W3[k * HID + c];
        g[c] = dv * acc;
    }
    t3[i] = make_uint4(packh2(g[0], g[1]), packh2(g[2], g[3]),
                       packh2(g[4], g[5]), packh2(g[6], g[7]));
}

// layer3: gather 8ch; epilogue b3->elu; fused mean-pool (no per-node output)
__global__ void agg3_kernel(const uint4* __restrict__ tab, const int* __restrict__ ptr,
                            const int* __restrict__ ssrc, const float* __restrict__ dinv,
                            const float* __restrict__ b3, double* __restrict__ pooled, int N) {
    int i = blockIdx.x * blockDim.x + threadIdx.x;
    float v[HID];
#pragma unroll
    for (int c = 0; c < HID; ++c) v[c] = 0.0f;
    if (i < N) {
        uint4 u = tab[i];
        float2 p0 = unpackh2(u.x), p1 = unpackh2(u.y), p2 = unpackh2(u.z), p3 = unpackh2(u.w);
        float s0 = p0.x, s1 = p0.y, s2 = p1.x, s3 = p1.y;
        float s4 = p2.x, s5 = p2.y, s6 = p3.x, s7 = p3.y;
        int e0 = ptr[i], e1 = ptr[i + 1];
#pragma unroll 4
        for (int k = e0; k < e1; ++k) {
            uint4 w = tab[ssrc[k]];
            float2 q0 = unpackh2(w.x), q1 = unpackh2(w.y), q2 = unpackh2(w.z), q3 = unpackh2(w.w);
            s0 += q0.x; s1 += q0.y; s2 += q1.x; s3 += q1.y;
            s4 += q2.x; s5 += q2.y; s6 += q3.x; s7 += q3.y;
        }
        float dv = dinv[i];
        v[0] = elu(dv * s0 + b3[0]); v[1] = elu(dv * s1 + b3[1]);
        v[2] = elu(dv * s2 + b3[2]); v[3] = elu(dv * s3 + b3[3]);
        v[4] = elu(dv * s4 + b3[4]); v[5] = elu(dv * s5 + b3[5]);
        v[6] = elu(dv * s6 + b3[6]); v[7] = elu(dv * s7 + b3[7]);
    }
#pragma unroll
    for (int c = 0; c < HID; ++c) {
        float s = v[c];
        for (int off = 32; off > 0; off >>= 1) s += __shfl_down(s, off);
        v[c] = s;
    }
    __shared__ float sm[4][HID];
    int lane = threadIdx.x & 63;
    int wv = threadIdx.x >> 6;
    if (lane == 0) {
#pragma unroll
        for (int c = 0; c < HID; ++c) sm[wv][c] = v[c];
    }
    __syncthreads();
    if (threadIdx.x == 0) {
#pragma unroll
        for (int c = 0; c < HID; ++c) {
            float s = sm[0][c] + sm[1][c] + sm[2][c] + sm[3][c];
            atomicAdd(&pooled[c], (double)s);
        }
    }
}

__global__ void head_kernel(const double* __restrict__ pooled, const float* __restrict__ Wr1,
                            const float* __restrict__ br1, const float* __restrict__ Wr2,
                            const float* __restrict__ br2, float* __restrict__ out, int N) {
    if (threadIdx.x != 0 || blockIdx.x != 0) return;
    float p[HID];
#pragma unroll
    for (int k = 0; k < HID; ++k) p[k] = (float)(pooled[k] / (double)N);
    float hdn[HID];
#pragma unroll
    for (int j = 0; j < HID; ++j) {
        float s = br1[j];
#pragma unroll
        for (int k = 0; k < HID; ++k) s += p[k] * Wr1[k * HID + j];
        hdn[j] = elu(s);
    }
    float v = br2[0];
#pragma unroll
    for (int j = 0; j < HID; ++j) v += hdn[j] * Wr2[j];
    out[0] = v;
}

extern "C" void kernel_launch(void* const* d_in, const int* in_sizes, int n_in,
                              void* d_out, int out_size, void* d_ws, size_t ws_size,
                              hipStream_t stream) {
    const float* x   = (const float*)d_in[0];
    const int*   ei  = (const int*)d_in[1];
    const float* W1  = (const float*)d_in[2];
    const float* b1  = (const float*)d_in[3];
    const float* W2  = (const float*)d_in[4];
    const float* b2  = (const float*)d_in[5];
    const float* W3  = (const float*)d_in[6];
    const float* b3  = (const float*)d_in[7];
    const float* Wr1 = (const float*)d_in[8];
    const float* br1 = (const float*)d_in[9];
    const float* Wr2 = (const float*)d_in[10];
    const float* br2 = (const float*)d_in[11];
    float* out = (float*)d_out;

    const int N = NNODES;
    const int E = in_sizes[1] / 2;
    const int* srcp = ei;      // edge_index[0]
    const int* dstp = ei + E;  // edge_index[1]

    // workspace layout (~86 MB)
    double* pooled    = (double*)d_ws;                       // 8 doubles
    uint4* t2         = (uint4*)(pooled + HID);              // N x 16B
    uint4* t3         = t2 + N;                              // N x 16B
    unsigned int* t1  = (unsigned int*)(t3 + N);             // N x 4B
    int* gbinhist     = (int*)(t1 + N);                      // NBIN
    int* binexcl      = gbinhist + NBIN;                     // NBIN
    int* bsum         = binexcl + NBIN;                      // 1024
    int* ptr_bins     = bsum + 1024;                         // NBIN+1
    int* gcursor      = ptr_bins + NBIN + 1;                 // NBIN
    int* ptr          = gcursor + NBIN;                      // N+1
    float* dinv       = (float*)(ptr + N + 1);               // N
    int* ssrc         = (int*)(dinv + N);                    // E

    hipMemsetAsync(gbinhist, 0, NBIN * sizeof(int), stream);
    hipMemsetAsync(pooled, 0, HID * sizeof(double), stream);

    const int BLK = 256;
    const int nodeGrid = (N + BLK - 1) / BLK;

    // CSR build
    binhist_kernel<<<128, 1024, 0, stream>>>(dstp, E, gbinhist);
    scan1_kernel<<<(NBIN + SCAN_BLK - 1) / SCAN_BLK, SCAN_BLK, 0, stream>>>(gbinhist, binexcl, bsum, NBIN);
    scan2_kernel<<<1, SCAN_BLK, 0, stream>>>(bsum, (NBIN + SCAN_BLK - 1) / SCAN_BLK);
    scan3b_kernel<<<(NBIN + BLK - 1) / BLK, BLK, 0, stream>>>(binexcl, bsum, ptr_bins, gcursor, E);
    binscatter_kernel<<<(E + CHUNK - 1) / CHUNK, 1024, 0, stream>>>(srcp, dstp, E, gcursor, ssrc);
    binsort_kernel<<<NBIN, 512, 0, stream>>>(ptr_bins, ssrc, ptr, dinv, x, t1, N, E);

    // 3 fused gather passes
    agg1_kernel<<<nodeGrid, BLK, 0, stream>>>(t1, ptr, ssrc, dinv, W1, b1, W2, t2, N);
    agg2_kernel<<<nodeGrid, BLK, 0, stream>>>(t2, ptr, ssrc, dinv, b2, W3, t3, N);
    agg3_kernel<<<nodeGrid, BLK, 0, stream>>>(t3, ptr, ssrc, dinv, b3, pooled, N);

    head_kernel<<<1, 64, 0, stream>>>(pooled, Wr1, br1, Wr2, br2, out, N);
}